// Round 4
// baseline (1998.463 us; speedup 1.0000x reference)
//
#include <hip/hip_runtime.h>

// GCN: 2-layer GraphConv, N=100000, E=1600000, 128 -> 128 -> 40 (fp32).
// Round 13: edge-parallel bucket aggregation. No CSR, no per-node wave mapping,
// no global atomics (R3 lesson: device atomics are memory-side, ~40B each).
//   histconv:  coarse dst+src bucket hists (LDS-aggregated) + x/W bf16 convert.
//   partition: dual counting-sort into 391 buckets of 256 nodes
//              (epartsD: src|dl<<17 in ws; epartsS: ushort src_local in d_out).
//   normpass:  per-bucket LDS hist of epartsS -> srcn (out-degree norm).
//   mega:      1 block/bucket: fp32 agg[256][128] in LDS (132 KB); edges
//              streamed in arbitrary order, ds_add_f32 accumulate + LDS indeg
//              count; then MFMA GEMM1(relu)+GEMM2 on the tile -> hwb (bf16).
//   agg2:      1 block/bucket: fp32 agg[256][40] in LDS; stream edges, add
//              80B hwb rows; epilogue out = dstn*agg + b2.
constexpr int NN   = 100000;
constexpr int NE   = 1600000;
constexpr int INF  = 128;
constexpr int NC   = 40;

constexpr int BKSH = 8;                        // 256 nodes per bucket
constexpr int NBK  = (NN + 255) / 256;         // 391 buckets
constexpr int EPB  = 4096;                     // edges per partition block
constexpr int PBLK = (NE + EPB - 1) / EPB;     // 391
constexpr int HB   = 391;                      // hist blocks in histconv

typedef __attribute__((ext_vector_type(8))) short short8;
typedef __attribute__((ext_vector_type(4))) float f32x4;

__device__ __forceinline__ float bflo(unsigned int u) { return __uint_as_float(u << 16); }
__device__ __forceinline__ float bfhi(unsigned int u) { return __uint_as_float(u & 0xffff0000u); }
__device__ __forceinline__ unsigned short f2bf(float f) {          // RNE
    unsigned int u = __float_as_uint(f);
    return (unsigned short)((u + 0x7fffu + ((u >> 16) & 1u)) >> 16);
}
__device__ __forceinline__ unsigned int pack2(float a, float b) {
    return (unsigned int)f2bf(a) | ((unsigned int)f2bf(b) << 16);
}

// blocks 0..HB-1: coarse dst-bucket AND src-bucket histograms (LDS aggregated).
// blocks HB..HB+6249: x (fp32) -> xh (bf16). +2 blocks: W1/W2 transpose->bf16.
__global__ __launch_bounds__(256) void histconv_kernel(const int* __restrict__ src,
                                                       const int* __restrict__ dst,
                                                       unsigned int* __restrict__ bcntD,
                                                       unsigned int* __restrict__ bcntS,
                                                       const float* __restrict__ x,
                                                       const float* __restrict__ W1,
                                                       const float* __restrict__ W2,
                                                       unsigned short* __restrict__ xh,
                                                       unsigned short* __restrict__ w1t,
                                                       unsigned short* __restrict__ w2t) {
    const int b = blockIdx.x;
    const int tid = threadIdx.x;
    if (b < HB) {
        __shared__ unsigned int hcD[NBK];
        __shared__ unsigned int hcS[NBK];
        for (int i = tid; i < NBK; i += 256) { hcD[i] = 0u; hcS[i] = 0u; }
        __syncthreads();
        int gid = b * 256 + tid;
        int stride = HB * 256;
        for (int e = gid; e < NE; e += stride) {
            atomicAdd(&hcD[dst[e] >> BKSH], 1u);
            atomicAdd(&hcS[src[e] >> BKSH], 1u);
        }
        __syncthreads();
        for (int i = tid; i < NBK; i += 256) {
            if (hcD[i]) atomicAdd(&bcntD[i], hcD[i]);
            if (hcS[i]) atomicAdd(&bcntS[i], hcS[i]);
        }
    } else if (b < HB + 6250) {
        int j = (b - HB) * 256 + tid;                // uint4 index, N*128/8 = 1.6M
        float4 v0 = ((const float4*)x)[2 * j];
        float4 v1 = ((const float4*)x)[2 * j + 1];
        uint4 o;
        o.x = pack2(v0.x, v0.y);
        o.y = pack2(v0.z, v0.w);
        o.z = pack2(v1.x, v1.y);
        o.w = pack2(v1.z, v1.w);
        ((uint4*)xh)[j] = o;
    } else if (b == HB + 6250) {
        for (int i = tid; i < 128 * 128; i += 256) {
            int k = i >> 7, n = i & 127;
            w1t[n * 128 + k] = f2bf(W1[i]);
        }
    } else {
        for (int i = tid; i < 48 * 128; i += 256) {
            int n = i >> 7, k = i & 127;
            w2t[i] = f2bf((n < NC) ? W2[k * NC + n] : 0.f);
        }
    }
}

// dual partition, 512 threads: dst-records (src | dst_local<<17) into epartsD,
// src-records (ushort src_local) into epartsS. LDS-staged -> coalesced dumps.
__global__ __launch_bounds__(512) void partition_kernel(const int* __restrict__ src,
                                                        const int* __restrict__ dst,
                                                        const unsigned int* __restrict__ bcntD,
                                                        const unsigned int* __restrict__ bcntS,
                                                        int* __restrict__ curD_g,
                                                        int* __restrict__ curS_g,
                                                        int* __restrict__ epartsD,
                                                        unsigned short* __restrict__ epartsS) {
    __shared__ int sc[512];
    __shared__ int cntD[NBK], gadjD[NBK], curD[NBK];
    __shared__ int cntS[NBK], gadjS[NBK], curS[NBK];
    __shared__ int baselD[NBK], baselS[NBK];
    __shared__ int stageD[EPB];
    __shared__ unsigned short stageS[EPB];
    __shared__ unsigned short bidD[EPB];
    __shared__ unsigned short bidS[EPB];
    const int tid = threadIdx.x;
    const int e0 = blockIdx.x * EPB;
    const int total = min(EPB, NE - e0);

    // self-scan of global bucket counts -> base offsets (dst then src)
    {
        int v = (tid < NBK) ? (int)bcntD[tid] : 0;
        sc[tid] = v;
        __syncthreads();
        for (int off = 1; off < 512; off <<= 1) {
            int t = (tid >= off) ? sc[tid - off] : 0;
            __syncthreads();
            sc[tid] += t;
            __syncthreads();
        }
        if (tid < NBK) baselD[tid] = sc[tid] - v;
        __syncthreads();
        v = (tid < NBK) ? (int)bcntS[tid] : 0;
        sc[tid] = v;
        __syncthreads();
        for (int off = 1; off < 512; off <<= 1) {
            int t = (tid >= off) ? sc[tid - off] : 0;
            __syncthreads();
            sc[tid] += t;
            __syncthreads();
        }
        if (tid < NBK) baselS[tid] = sc[tid] - v;
    }
    for (int i = tid; i < NBK; i += 512) { cntD[i] = 0; cntS[i] = 0; }
    __syncthreads();
    // phase A: count per bucket (both keys)
    for (int i = tid; i < total; i += 512) {
        atomicAdd(&cntD[dst[e0 + i] >> BKSH], 1);
        atomicAdd(&cntS[src[e0 + i] >> BKSH], 1);
    }
    __syncthreads();
    // exclusive scans of cntD, cntS; reserve global ranges
    {
        int v = (tid < NBK) ? cntD[tid] : 0;
        sc[tid] = v;
        __syncthreads();
        for (int off = 1; off < 512; off <<= 1) {
            int t = (tid >= off) ? sc[tid - off] : 0;
            __syncthreads();
            sc[tid] += t;
            __syncthreads();
        }
        if (tid < NBK) {
            int excl = sc[tid] - v;
            curD[tid] = excl;
            int g = (v > 0) ? atomicAdd(&curD_g[tid], v) : 0;   // zero-based
            gadjD[tid] = baselD[tid] + g - excl;
        }
        __syncthreads();
        v = (tid < NBK) ? cntS[tid] : 0;
        sc[tid] = v;
        __syncthreads();
        for (int off = 1; off < 512; off <<= 1) {
            int t = (tid >= off) ? sc[tid - off] : 0;
            __syncthreads();
            sc[tid] += t;
            __syncthreads();
        }
        if (tid < NBK) {
            int excl = sc[tid] - v;
            curS[tid] = excl;
            int g = (v > 0) ? atomicAdd(&curS_g[tid], v) : 0;
            gadjS[tid] = baselS[tid] + g - excl;
        }
    }
    __syncthreads();
    // phase B: re-read edges, stage grouped by bucket (both keys)
    for (int i = tid; i < total; i += 512) {
        int s = src[e0 + i];
        int d = dst[e0 + i];
        int bD = d >> BKSH;
        int offD = atomicAdd(&curD[bD], 1);
        stageD[offD] = s | ((d - (bD << BKSH)) << 17);
        bidD[offD] = (unsigned short)bD;
        int bS = s >> BKSH;
        int offS = atomicAdd(&curS[bS], 1);
        stageS[offS] = (unsigned short)(s - (bS << BKSH));
        bidS[offS] = (unsigned short)bS;
    }
    __syncthreads();
    // dumps: consecutive j within a bucket-run -> consecutive global addresses
    for (int j = tid; j < total; j += 512) {
        int b = bidD[j];
        epartsD[gadjD[b] + j] = stageD[j];
    }
    for (int j = tid; j < total; j += 512) {
        int b = bidS[j];
        epartsS[gadjS[b] + j] = stageS[j];
    }
}

// per src-bucket: LDS hist of epartsS -> srcn (out-degree norm).
__global__ __launch_bounds__(512) void normpass_kernel(const unsigned int* __restrict__ bcntS,
                                                       const unsigned short* __restrict__ epartsS,
                                                       float* __restrict__ srcn) {
    __shared__ int sc[512];
    __shared__ int histS[256];
    __shared__ int base_s, cnt_s;
    const int tid = threadIdx.x;
    const int b = blockIdx.x;
    {
        int v = (tid < NBK) ? (int)bcntS[tid] : 0;
        sc[tid] = v;
        __syncthreads();
        for (int off = 1; off < 512; off <<= 1) {
            int t = (tid >= off) ? sc[tid - off] : 0;
            __syncthreads();
            sc[tid] += t;
            __syncthreads();
        }
        if (tid == b) { base_s = sc[b] - v; cnt_s = v; }
        __syncthreads();
    }
    const int base = base_s;
    const int cnt = cnt_s;
    if (tid < 256) histS[tid] = 0;
    __syncthreads();
    for (int j = tid; j < cnt; j += 512)
        atomicAdd(&histS[(int)epartsS[base + j]], 1);
    __syncthreads();
    const int n0 = b << BKSH;
    const int nloc = min(256, NN - n0);
    if (tid < nloc)
        srcn[n0 + tid] = rsqrtf(fmaxf((float)histS[tid], 1.0f));
}

// 1 block per 256-node dst bucket. Phase 1: stream the bucket's edges in
// arbitrary order; per edge fetch xh[src] (256B, 16 lanes x uint4), scale by
// srcn[src], ds_add_f32 into agg[dst_local] (fp32, stride 129 to stagger
// banks); LDS in-degree count on the side. Phase 2: A-frags = dn*agg -> bf16
// regs; barrier; GEMM1 (+b1, relu) -> h bf16 overwrites agg (wave-own rows);
// GEMM2 -> hwb with srcn fold. B-frags straight from global w1t/w2t (L2-hot).
__global__ __launch_bounds__(512, 1) void mega_kernel(const unsigned int* __restrict__ bcntD,
                                                      const int* __restrict__ epartsD,
                                                      const unsigned short* __restrict__ xh,
                                                      const float* __restrict__ srcn,
                                                      const unsigned short* __restrict__ w1t,
                                                      const unsigned short* __restrict__ w2t,
                                                      const float* __restrict__ b1,
                                                      unsigned short* __restrict__ hwb) {
    __shared__ float agg[256 * 129];     // 132 KB, +1 f32 row pad
    __shared__ int cnti[256];
    __shared__ float b1l[128];
    __shared__ float snl[256];
    __shared__ int sc[512];
    __shared__ int base_s, cnt_s;
    const int tid = threadIdx.x;
    const int b = blockIdx.x;
    const int n0 = b << BKSH;
    {
        int v = (tid < NBK) ? (int)bcntD[tid] : 0;
        sc[tid] = v;
        __syncthreads();
        for (int off = 1; off < 512; off <<= 1) {
            int t = (tid >= off) ? sc[tid - off] : 0;
            __syncthreads();
            sc[tid] += t;
            __syncthreads();
        }
        if (tid == b) { base_s = sc[b] - v; cnt_s = v; }
        __syncthreads();
    }
    const int base = base_s;
    const int cnt = cnt_s;

    for (int i = tid; i < 256 * 129; i += 512) agg[i] = 0.f;
    if (tid < 256) {
        cnti[tid] = 0;
        int g = n0 + tid;
        snl[tid] = (g < NN) ? srcn[g] : 0.f;
    }
    if (tid >= 256 && tid < 384) b1l[tid - 256] = b1[tid - 256];
    __syncthreads();

    // ---- phase 1: edge-parallel aggregation ----
    const int wv   = tid >> 6;
    const int lane = tid & 63;
    const int quad = lane >> 4;       // 4 edge slots per wave step
    const int l16  = lane & 15;       // uint4 index within 256 B row
    for (int eb = wv * 16; eb < cnt; eb += 128) {
        int  s[4], dl[4];
        bool vl[4];
#pragma unroll
        for (int t = 0; t < 4; ++t) {
            int idx = eb + t * 4 + quad;
            vl[t] = idx < cnt;
            int rec = epartsD[base + (vl[t] ? idx : 0)];
            s[t] = rec & 0x1FFFF;
            dl[t] = rec >> 17;
        }
        float n[4];
        uint4 u[4];
#pragma unroll
        for (int t = 0; t < 4; ++t) {
            n[t] = vl[t] ? srcn[s[t]] : 0.f;
            u[t] = ((const uint4*)(xh + (size_t)s[t] * INF))[l16];
        }
#pragma unroll
        for (int t = 0; t < 4; ++t) {
            if (vl[t] && l16 == 0) atomicAdd(&cnti[dl[t]], 1);
            float* a = &agg[dl[t] * 129 + l16 * 8];
            atomicAdd(a + 0, bflo(u[t].x) * n[t]);
            atomicAdd(a + 1, bfhi(u[t].x) * n[t]);
            atomicAdd(a + 2, bflo(u[t].y) * n[t]);
            atomicAdd(a + 3, bfhi(u[t].y) * n[t]);
            atomicAdd(a + 4, bflo(u[t].z) * n[t]);
            atomicAdd(a + 5, bfhi(u[t].z) * n[t]);
            atomicAdd(a + 6, bflo(u[t].w) * n[t]);
            atomicAdd(a + 7, bfhi(u[t].w) * n[t]);
        }
    }
    __syncthreads();   // agg + cnti complete

    // ---- phase 2: GEMM1 (+relu) and GEMM2, 32 rows per wave ----
    const int lrow  = lane & 15;
    const int lquad = lane >> 4;
    const int wr0   = wv * 32;

    short8 af[2][4];
#pragma unroll
    for (int rt = 0; rt < 2; ++rt) {
        int row = wr0 + rt * 16 + lrow;
        float dv = rsqrtf(fmaxf((float)cnti[row], 1.0f));
#pragma unroll
        for (int ks = 0; ks < 4; ++ks) {
            const float* ap = &agg[row * 129 + ks * 32 + lquad * 8];
            union { unsigned int u[4]; short8 v; } tmp;
#pragma unroll
            for (int j = 0; j < 4; ++j)
                tmp.u[j] = pack2(ap[2 * j] * dv, ap[2 * j + 1] * dv);
            af[rt][ks] = tmp.v;
        }
    }
    __syncthreads();   // all A-frag reads done before h overwrites agg

    unsigned short* hbuf = (unsigned short*)agg;   // h[row][col], stride 128
#pragma unroll
    for (int nt = 0; nt < 8; ++nt) {
        f32x4 a0 = {0.f, 0.f, 0.f, 0.f};
        f32x4 a1 = {0.f, 0.f, 0.f, 0.f};
#pragma unroll
        for (int ks = 0; ks < 4; ++ks) {
            short8 bfr = *(const short8*)&w1t[(nt * 16 + lrow) * 128 + ks * 32 + lquad * 8];
            a0 = __builtin_amdgcn_mfma_f32_16x16x32_bf16(af[0][ks], bfr, a0, 0, 0, 0);
            a1 = __builtin_amdgcn_mfma_f32_16x16x32_bf16(af[1][ks], bfr, a1, 0, 0, 0);
        }
        int col = nt * 16 + lrow;
        float bb = b1l[col];
#pragma unroll
        for (int i = 0; i < 4; ++i) {
            int r0 = wr0 + lquad * 4 + i;
            int r1 = r0 + 16;
            hbuf[r0 * 128 + col] = f2bf(fmaxf(a0[i] + bb, 0.f));
            hbuf[r1 * 128 + col] = f2bf(fmaxf(a1[i] + bb, 0.f));
        }
    }
    // wave reads back only its own h rows -> no barrier

    short8 hf[2][4];
#pragma unroll
    for (int rt = 0; rt < 2; ++rt)
#pragma unroll
        for (int ks = 0; ks < 4; ++ks)
            hf[rt][ks] = *(const short8*)&hbuf[(wr0 + rt * 16 + lrow) * 128 + ks * 32 + lquad * 8];
#pragma unroll
    for (int nt = 0; nt < 3; ++nt) {
        f32x4 a0 = {0.f, 0.f, 0.f, 0.f};
        f32x4 a1 = {0.f, 0.f, 0.f, 0.f};
#pragma unroll
        for (int ks = 0; ks < 4; ++ks) {
            short8 bfr = *(const short8*)&w2t[(nt * 16 + lrow) * 128 + ks * 32 + lquad * 8];
            a0 = __builtin_amdgcn_mfma_f32_16x16x32_bf16(hf[0][ks], bfr, a0, 0, 0, 0);
            a1 = __builtin_amdgcn_mfma_f32_16x16x32_bf16(hf[1][ks], bfr, a1, 0, 0, 0);
        }
        int col = nt * 16 + lrow;
        if (col < NC) {
#pragma unroll
            for (int i = 0; i < 4; ++i) {
                int r0 = wr0 + lquad * 4 + i;
                int r1 = r0 + 16;
                if (n0 + r0 < NN)
                    hwb[(size_t)(n0 + r0) * NC + col] = f2bf(a0[i] * snl[r0]);
                if (n0 + r1 < NN)
                    hwb[(size_t)(n0 + r1) * NC + col] = f2bf(a1[i] * snl[r1]);
            }
        }
    }
}

// 1 block per 256-node dst bucket, layer 2: stream edges, fetch hwb[src]
// (80 B, 5 lanes x uint4), ds_add_f32 into agg[dst_local][40]; LDS in-degree
// count; epilogue out = dstn*agg + b2 (fp32, coalesced).
__global__ __launch_bounds__(512) void agg2_kernel(const unsigned int* __restrict__ bcntD,
                                                   const int* __restrict__ epartsD,
                                                   const unsigned short* __restrict__ hwb,
                                                   const float* __restrict__ b2,
                                                   float* __restrict__ out) {
    __shared__ float aggo[256 * 40];     // 40 KB
    __shared__ int cnto[256];
    __shared__ float b2l[40];
    __shared__ int sc[512];
    __shared__ int base_s, cnt_s;
    const int tid = threadIdx.x;
    const int b = blockIdx.x;
    const int n0 = b << BKSH;
    {
        int v = (tid < NBK) ? (int)bcntD[tid] : 0;
        sc[tid] = v;
        __syncthreads();
        for (int off = 1; off < 512; off <<= 1) {
            int t = (tid >= off) ? sc[tid - off] : 0;
            __syncthreads();
            sc[tid] += t;
            __syncthreads();
        }
        if (tid == b) { base_s = sc[b] - v; cnt_s = v; }
        __syncthreads();
    }
    const int base = base_s;
    const int cnt = cnt_s;

    for (int i = tid; i < 256 * 40; i += 512) aggo[i] = 0.f;
    if (tid < 256) cnto[tid] = 0;
    if (tid >= 256 && tid < 296) b2l[tid - 256] = b2[tid - 256];
    __syncthreads();

    const int wv   = tid >> 6;
    const int lane = tid & 63;
    const int g    = lane / 5;        // edge slot group 0..11 (g==12: idle)
    const int l5   = lane - g * 5;    // uint4 index within 80 B row
    const bool act = (g < 12);
    for (int eb = wv * 24; eb < cnt; eb += 192) {
        int  s[2], dl[2];
        float m[2];
#pragma unroll
        for (int t = 0; t < 2; ++t) {
            int idx = eb + t * 12 + g;
            bool v = act && (idx < cnt);
            int rec = epartsD[base + (v ? idx : 0)];
            s[t] = rec & 0x1FFFF;
            dl[t] = rec >> 17;
            m[t] = v ? 1.f : 0.f;
            if (v && l5 == 0) atomicAdd(&cnto[dl[t]], 1);
        }
        uint4 u[2];
#pragma unroll
        for (int t = 0; t < 2; ++t)
            u[t] = ((const uint4*)(hwb + (size_t)s[t] * NC))[l5];
#pragma unroll
        for (int t = 0; t < 2; ++t) {
            float* a = &aggo[dl[t] * 40 + l5 * 8];
            atomicAdd(a + 0, bflo(u[t].x) * m[t]);
            atomicAdd(a + 1, bfhi(u[t].x) * m[t]);
            atomicAdd(a + 2, bflo(u[t].y) * m[t]);
            atomicAdd(a + 3, bfhi(u[t].y) * m[t]);
            atomicAdd(a + 4, bflo(u[t].z) * m[t]);
            atomicAdd(a + 5, bfhi(u[t].z) * m[t]);
            atomicAdd(a + 6, bflo(u[t].w) * m[t]);
            atomicAdd(a + 7, bfhi(u[t].w) * m[t]);
        }
    }
    __syncthreads();

    const int nloc = min(256, NN - n0);
    for (int i = tid; i < nloc * 40; i += 512) {
        int node = i / 40;
        int c = i - node * 40;
        float dnv = rsqrtf(fmaxf((float)cnto[node], 1.0f));
        out[(size_t)(n0 + node) * NC + c] = aggo[i] * dnv + b2l[c];
    }
}

extern "C" void kernel_launch(void* const* d_in, const int* in_sizes, int n_in,
                              void* d_out, int out_size, void* d_ws, size_t ws_size,
                              hipStream_t stream) {
    const float* x   = (const float*)d_in[0];
    const float* W1  = (const float*)d_in[1];
    const float* b1  = (const float*)d_in[2];
    const float* W2  = (const float*)d_in[3];
    const float* b2  = (const float*)d_in[4];
    const int*   src = (const int*)d_in[5];
    const int*   dst = (const int*)d_in[6];
    float* out = (float*)d_out;

    // workspace (4B units):
    // srcn[NN] | bcntD[512] | bcntS[512] | curDg[512] | curSg[512] |
    // epartsD[NE] | xh[NN*64] | w1t[8192] | w2t[3072] | hwb[NN*20]
    float* srcn = (float*)d_ws;
    unsigned int* bcntD = (unsigned int*)(srcn + NN);
    unsigned int* bcntS = bcntD + 512;
    int* curDg = (int*)(bcntS + 512);
    int* curSg = curDg + 512;
    int* epartsD = curSg + 512;                    // NN+2048 words: 16B aligned
    unsigned short* xh  = (unsigned short*)(epartsD + NE);
    unsigned short* w1t = xh + (size_t)NN * INF;
    unsigned short* w2t = w1t + 128 * 128;
    unsigned short* hwb = w2t + 48 * 128;

    // epartsS lives in d_out (3.2 MB of 16 MB) — dead before agg2 writes out
    unsigned short* epartsS = (unsigned short*)d_out;

    hipMemsetAsync(bcntD, 0, 2048 * sizeof(int), stream);  // bcntD|bcntS|curDg|curSg

    histconv_kernel<<<HB + 6252, 256, 0, stream>>>(src, dst, bcntD, bcntS,
                                                   x, W1, W2, xh, w1t, w2t);
    partition_kernel<<<PBLK, 512, 0, stream>>>(src, dst, bcntD, bcntS, curDg, curSg,
                                               epartsD, epartsS);
    normpass_kernel<<<NBK, 512, 0, stream>>>(bcntS, epartsS, srcn);
    mega_kernel<<<NBK, 512, 0, stream>>>(bcntD, epartsD, xh, srcn,
                                         w1t, w2t, b1, hwb);
    agg2_kernel<<<NBK, 512, 0, stream>>>(bcntD, epartsD, hwb, b2, out);
}

// Round 5
// 307.691 us; speedup vs baseline: 6.4950x; 6.4950x over previous
//
#include <hip/hip_runtime.h>

// GCN: 2-layer GraphConv, N=100000, E=1600000, 128 -> 128 -> 40 (fp32).
// Round 14: recover R2 pipeline (best 318.7), two targeted fixes:
//   fused:   pairwise dual-stream gather — 8 node-pairs per wave, two
//            independent 24-edge predicated batches in flight (12 row loads),
//            row_ptr hoisted via one wave load + shfl. Register accumulation
//            only (R3: no global atomics; R4: no LDS-atomic scatter).
//   build:   basescan kernel precomputes bucket bases; partition/pass2 drop
//            their per-block 512-wide self-scans.
//   histconv/gather2: unchanged from R2.
constexpr int NN   = 100000;
constexpr int NE   = 1600000;
constexpr int INF  = 128;
constexpr int NC   = 40;

constexpr int BKSH = 9;                        // 512 nodes per coarse bucket
constexpr int NBK  = (NN + 511) / 512;         // 196 buckets
constexpr int EPB  = 4096;                     // edges per partition block
constexpr int PBLK = (NE + EPB - 1) / EPB;     // 391
constexpr int CAP  = 14336;                    // pass2 LDS esrc capacity (56 KB)
constexpr int HB   = 391;                      // hist blocks in merged kernel

typedef __attribute__((ext_vector_type(8))) short short8;
typedef __attribute__((ext_vector_type(4))) float f32x4;

__device__ __forceinline__ float bflo(unsigned int u) { return __uint_as_float(u << 16); }
__device__ __forceinline__ float bfhi(unsigned int u) { return __uint_as_float(u & 0xffff0000u); }
__device__ __forceinline__ unsigned short f2bf(float f) {          // RNE
    unsigned int u = __float_as_uint(f);
    return (unsigned short)((u + 0x7fffu + ((u >> 16) & 1u)) >> 16);
}
__device__ __forceinline__ unsigned int pack2(float a, float b) {
    return (unsigned int)f2bf(a) | ((unsigned int)f2bf(b) << 16);
}

// blocks 0..HB-1: coarse dst-bucket AND src-bucket histograms (LDS aggregated).
// blocks HB..HB+6249: x (fp32) -> xh (bf16). +2 blocks: W1/W2 transpose->bf16.
__global__ __launch_bounds__(256) void histconv_kernel(const int* __restrict__ src,
                                                       const int* __restrict__ dst,
                                                       unsigned int* __restrict__ bcntD,
                                                       unsigned int* __restrict__ bcntS,
                                                       const float* __restrict__ x,
                                                       const float* __restrict__ W1,
                                                       const float* __restrict__ W2,
                                                       unsigned short* __restrict__ xh,
                                                       unsigned short* __restrict__ w1t,
                                                       unsigned short* __restrict__ w2t) {
    const int b = blockIdx.x;
    const int tid = threadIdx.x;
    if (b < HB) {
        __shared__ unsigned int hcD[NBK];
        __shared__ unsigned int hcS[NBK];
        for (int i = tid; i < NBK; i += 256) { hcD[i] = 0u; hcS[i] = 0u; }
        __syncthreads();
        int gid = b * 256 + tid;
        int stride = HB * 256;
        for (int e = gid; e < NE; e += stride) {
            atomicAdd(&hcD[dst[e] >> BKSH], 1u);
            atomicAdd(&hcS[src[e] >> BKSH], 1u);
        }
        __syncthreads();
        for (int i = tid; i < NBK; i += 256) {
            if (hcD[i]) atomicAdd(&bcntD[i], hcD[i]);
            if (hcS[i]) atomicAdd(&bcntS[i], hcS[i]);
        }
    } else if (b < HB + 6250) {
        int j = (b - HB) * 256 + tid;                // uint4 index, N*128/8 = 1.6M
        float4 v0 = ((const float4*)x)[2 * j];
        float4 v1 = ((const float4*)x)[2 * j + 1];
        uint4 o;
        o.x = pack2(v0.x, v0.y);
        o.y = pack2(v0.z, v0.w);
        o.z = pack2(v1.x, v1.y);
        o.w = pack2(v1.z, v1.w);
        ((uint4*)xh)[j] = o;
    } else if (b == HB + 6250) {
        for (int i = tid; i < 128 * 128; i += 256) {
            int k = i >> 7, n = i & 127;
            w1t[n * 128 + k] = f2bf(W1[i]);
        }
    } else {
        for (int i = tid; i < 48 * 128; i += 256) {
            int n = i >> 7, k = i & 127;
            w2t[i] = f2bf((n < NC) ? W2[k * NC + n] : 0.f);
        }
    }
}

// 1 block: exclusive scans of the 196 bucket counts (dst and src sides).
__global__ __launch_bounds__(256) void basescan_kernel(const unsigned int* __restrict__ bcntD,
                                                       const unsigned int* __restrict__ bcntS,
                                                       int* __restrict__ baseD,
                                                       int* __restrict__ baseS) {
    __shared__ int sc[256];
    const int tid = threadIdx.x;
    int v = (tid < NBK) ? (int)bcntD[tid] : 0;
    sc[tid] = v;
    __syncthreads();
    for (int off = 1; off < 256; off <<= 1) {
        int t = (tid >= off) ? sc[tid - off] : 0;
        __syncthreads();
        sc[tid] += t;
        __syncthreads();
    }
    if (tid < NBK) baseD[tid] = sc[tid] - v;
    __syncthreads();
    v = (tid < NBK) ? (int)bcntS[tid] : 0;
    sc[tid] = v;
    __syncthreads();
    for (int off = 1; off < 256; off <<= 1) {
        int t = (tid >= off) ? sc[tid - off] : 0;
        __syncthreads();
        sc[tid] += t;
        __syncthreads();
    }
    if (tid < NBK) baseS[tid] = sc[tid] - v;
}

// dual partition: dst-records (src | dst_local<<17) into epartsD, src-records
// (ushort src_local) into epartsS. Both LDS-staged -> coalesced run dumps.
// Bucket bases precomputed (basescan) — no per-block self-scans.
__global__ __launch_bounds__(256) void partition_kernel(const int* __restrict__ src,
                                                        const int* __restrict__ dst,
                                                        const int* __restrict__ baseD,
                                                        const int* __restrict__ baseS,
                                                        int* __restrict__ curD_g,
                                                        int* __restrict__ curS_g,
                                                        int* __restrict__ epartsD,
                                                        unsigned short* __restrict__ epartsS) {
    __shared__ int sc[256];
    __shared__ int cntD[NBK], gadjD[NBK], curD[NBK];
    __shared__ int cntS[NBK], gadjS[NBK], curS[NBK];
    __shared__ int stageD[EPB];
    __shared__ unsigned short stageS[EPB];
    __shared__ unsigned char bidD[EPB];
    __shared__ unsigned char bidS[EPB];
    const int tid = threadIdx.x;
    const int e0 = blockIdx.x * EPB;
    const int total = min(EPB, NE - e0);

    for (int i = tid; i < NBK; i += 256) { cntD[i] = 0; cntS[i] = 0; }
    __syncthreads();
    // phase A: count per bucket (both keys)
    for (int i = tid; i < total; i += 256) {
        atomicAdd(&cntD[dst[e0 + i] >> BKSH], 1);
        atomicAdd(&cntS[src[e0 + i] >> BKSH], 1);
    }
    __syncthreads();
    // exclusive scans of cntD, cntS; reserve global ranges
    {
        int v = (tid < NBK) ? cntD[tid] : 0;
        sc[tid] = v;
        __syncthreads();
        for (int off = 1; off < 256; off <<= 1) {
            int t = (tid >= off) ? sc[tid - off] : 0;
            __syncthreads();
            sc[tid] += t;
            __syncthreads();
        }
        if (tid < NBK) {
            int excl = sc[tid] - v;
            curD[tid] = excl;
            int g = (v > 0) ? atomicAdd(&curD_g[tid], v) : 0;   // zero-based
            gadjD[tid] = baseD[tid] + g - excl;
        }
        __syncthreads();
        v = (tid < NBK) ? cntS[tid] : 0;
        sc[tid] = v;
        __syncthreads();
        for (int off = 1; off < 256; off <<= 1) {
            int t = (tid >= off) ? sc[tid - off] : 0;
            __syncthreads();
            sc[tid] += t;
            __syncthreads();
        }
        if (tid < NBK) {
            int excl = sc[tid] - v;
            curS[tid] = excl;
            int g = (v > 0) ? atomicAdd(&curS_g[tid], v) : 0;
            gadjS[tid] = baseS[tid] + g - excl;
        }
    }
    __syncthreads();
    // phase B: re-read edges, stage grouped by bucket (both keys)
    for (int i = tid; i < total; i += 256) {
        int s = src[e0 + i];
        int d = dst[e0 + i];
        int bD = d >> BKSH;
        int offD = atomicAdd(&curD[bD], 1);
        stageD[offD] = s | ((d - (bD << BKSH)) << 17);
        bidD[offD] = (unsigned char)bD;
        int bS = s >> BKSH;
        int offS = atomicAdd(&curS[bS], 1);
        stageS[offS] = (unsigned short)(s - (bS << BKSH));
        bidS[offS] = (unsigned char)bS;
    }
    __syncthreads();
    // dumps: consecutive j within a bucket-run -> consecutive global addresses
    for (int j = tid; j < total; j += 256) {
        int b = bidD[j];
        epartsD[gadjD[b] + j] = stageD[j];
    }
    for (int j = tid; j < total; j += 256) {
        int b = bidS[j];
        epartsS[gadjS[b] + j] = stageS[j];
    }
}

// per-bucket: dst CSR (hist+scan+LDS scatter -> row_ptr, dstn, esrc) AND
// src out-degree hist -> srcn. Bases read from basescan output.
__global__ __launch_bounds__(512) void pass2_kernel(const int* __restrict__ epartsD,
                                                    const unsigned short* __restrict__ epartsS,
                                                    const int* __restrict__ baseD,
                                                    const int* __restrict__ baseS_g,
                                                    const unsigned int* __restrict__ bcntD,
                                                    const unsigned int* __restrict__ bcntS,
                                                    int* __restrict__ row_ptr,
                                                    int* __restrict__ esrc,
                                                    float* __restrict__ srcn,
                                                    float* __restrict__ dstn) {
    __shared__ int hist[512];
    __shared__ int cur[512];
    __shared__ int histS[512];
    __shared__ int lesrc[CAP];
    const int tid = threadIdx.x;
    const int b = blockIdx.x;

    const int base  = baseD[b];
    const int cnt   = (int)bcntD[b];
    const int baseS = baseS_g[b];
    const int cntS  = (int)bcntS[b];
    const int n0 = b << BKSH;
    const int nloc = min(512, NN - n0);

    hist[tid] = 0;
    histS[tid] = 0;
    __syncthreads();
    for (int j = tid; j < cnt; j += 512)
        atomicAdd(&hist[epartsD[base + j] >> 17], 1);
    for (int j = tid; j < cntS; j += 512)
        atomicAdd(&histS[(int)epartsS[baseS + j]], 1);
    __syncthreads();
    int myc = hist[tid];
    int mycS = histS[tid];
    for (int off = 1; off < 512; off <<= 1) {
        int t = (tid >= off) ? hist[tid - off] : 0;
        __syncthreads();
        hist[tid] += t;
        __syncthreads();
    }
    int excl = hist[tid] - myc;
    cur[tid] = excl;
    if (tid < nloc) {
        int g = n0 + tid;
        row_ptr[g] = base + excl;
        dstn[g] = rsqrtf(fmaxf((float)myc, 1.0f));    // dst_norm (in-degree)
        srcn[g] = rsqrtf(fmaxf((float)mycS, 1.0f));   // src_norm (out-degree)
    }
    if (b == NBK - 1 && tid == 0) row_ptr[NN] = NE;
    __syncthreads();
    if (cnt <= CAP) {
        for (int j = tid; j < cnt; j += 512) {
            int rec = epartsD[base + j];
            int pos = atomicAdd(&cur[rec >> 17], 1);
            lesrc[pos] = rec & 0x1FFFF;
        }
        __syncthreads();
        for (int j = tid; j < cnt; j += 512) esrc[base + j] = lesrc[j];
    } else {
        for (int j = tid; j < cnt; j += 512) {
            int rec = epartsD[base + j];
            int pos = atomicAdd(&cur[rec >> 17], 1);
            esrc[base + pos] = rec & 0x1FFFF;
        }
    }
}

// Fused gather1 + GEMM1 + GEMM2. 64 nodes/block, 4 waves, wave-private 16 rows.
// Phase 1 (R14): 8 node-PAIRS per wave; per pair, two independent 24-edge
//   predicated batches run concurrently (12 uint4 row loads + 12 srcn loads
//   in flight). row_ptr values hoisted once per wave via lane load + shfl.
//   Register accumulation; lanes<16 write both bf16 rows into wave-own At.
// Phase 2: MFMA 16x16x32 bf16; B-frags straight from global w1t/w2t (L2-hot).
__global__ __launch_bounds__(256, 4) void fused_kernel(const int* __restrict__ row_ptr,
                                                       const int* __restrict__ esrc,
                                                       const unsigned short* __restrict__ xh,
                                                       const float* __restrict__ srcn,
                                                       const unsigned short* __restrict__ w1t,
                                                       const unsigned short* __restrict__ w2t,
                                                       const float* __restrict__ b1,
                                                       const float* __restrict__ dstn,
                                                       unsigned short* __restrict__ hwb) {
    __shared__ unsigned short At[64 * 128];    // 16 KB: agg tile, then h tile
    __shared__ float dn[64], sn[64], b1l[128];
    const int tid  = threadIdx.x;
    const int r0   = blockIdx.x * 64;
    const int wv   = tid >> 6;
    const int lane = tid & 63;

    if (tid < 64) {
        int r = r0 + tid;
        dn[tid] = (r < NN) ? dstn[r] : 0.f;
        sn[tid] = (r < NN) ? srcn[r] : 0.f;
    }
    if (tid >= 64 && tid < 192) b1l[tid - 64] = b1[tid - 64];
    __syncthreads();

    // ---- phase 1: gather 16 nodes (8 pairs) into wave-private At rows ----
    const int quad = lane >> 4;       // edge-slot group 0..3
    const int l16  = lane & 15;       // uint4 index within 256 B row
    const int n0w  = r0 + wv * 16;
    // hoist row_ptr[n0w .. n0w+16] (17 values; OOB nodes clamp to row_ptr[NN])
    const int rpv = row_ptr[min(n0w + min(lane, 16), NN)];

    for (int p = 0; p < 8; ++p) {
        const int begA = __shfl(rpv, 2 * p);
        const int endA = __shfl(rpv, 2 * p + 1);
        const int begB = endA;
        const int endB = __shfl(rpv, 2 * p + 2);
        float aA0 = 0.f, aA1 = 0.f, aA2 = 0.f, aA3 = 0.f;
        float aA4 = 0.f, aA5 = 0.f, aA6 = 0.f, aA7 = 0.f;
        float aB0 = 0.f, aB1 = 0.f, aB2 = 0.f, aB3 = 0.f;
        float aB4 = 0.f, aB5 = 0.f, aB6 = 0.f, aB7 = 0.f;
        for (int eA = begA, eB = begB; eA < endA || eB < endB; eA += 24, eB += 24) {
            const int remA = endA - eA;
            const int remB = endB - eB;
            int sA[6], sB[6];
#pragma unroll
            for (int t = 0; t < 6; ++t) {
                int slot = t * 4 + quad;
                sA[t] = esrc[(slot < remA) ? (eA + slot) : 0];
                sB[t] = esrc[(slot < remB) ? (eB + slot) : 0];
            }
            float nA[6], nB[6];
            uint4 uA[6], uB[6];
#pragma unroll
            for (int t = 0; t < 6; ++t) {
                int slot = t * 4 + quad;
                nA[t] = (slot < remA) ? srcn[sA[t]] : 0.f;
                nB[t] = (slot < remB) ? srcn[sB[t]] : 0.f;
                uA[t] = ((const uint4*)(xh + (size_t)sA[t] * INF))[l16];
                uB[t] = ((const uint4*)(xh + (size_t)sB[t] * INF))[l16];
            }
#pragma unroll
            for (int t = 0; t < 6; ++t) {
                aA0 += bflo(uA[t].x) * nA[t]; aA1 += bfhi(uA[t].x) * nA[t];
                aA2 += bflo(uA[t].y) * nA[t]; aA3 += bfhi(uA[t].y) * nA[t];
                aA4 += bflo(uA[t].z) * nA[t]; aA5 += bfhi(uA[t].z) * nA[t];
                aA6 += bflo(uA[t].w) * nA[t]; aA7 += bfhi(uA[t].w) * nA[t];
                aB0 += bflo(uB[t].x) * nB[t]; aB1 += bfhi(uB[t].x) * nB[t];
                aB2 += bflo(uB[t].y) * nB[t]; aB3 += bfhi(uB[t].y) * nB[t];
                aB4 += bflo(uB[t].z) * nB[t]; aB5 += bfhi(uB[t].z) * nB[t];
                aB6 += bflo(uB[t].w) * nB[t]; aB7 += bfhi(uB[t].w) * nB[t];
            }
        }
        aA0 += __shfl_down(aA0, 32); aA1 += __shfl_down(aA1, 32);
        aA2 += __shfl_down(aA2, 32); aA3 += __shfl_down(aA3, 32);
        aA4 += __shfl_down(aA4, 32); aA5 += __shfl_down(aA5, 32);
        aA6 += __shfl_down(aA6, 32); aA7 += __shfl_down(aA7, 32);
        aB0 += __shfl_down(aB0, 32); aB1 += __shfl_down(aB1, 32);
        aB2 += __shfl_down(aB2, 32); aB3 += __shfl_down(aB3, 32);
        aB4 += __shfl_down(aB4, 32); aB5 += __shfl_down(aB5, 32);
        aB6 += __shfl_down(aB6, 32); aB7 += __shfl_down(aB7, 32);
        aA0 += __shfl_down(aA0, 16); aA1 += __shfl_down(aA1, 16);
        aA2 += __shfl_down(aA2, 16); aA3 += __shfl_down(aA3, 16);
        aA4 += __shfl_down(aA4, 16); aA5 += __shfl_down(aA5, 16);
        aA6 += __shfl_down(aA6, 16); aA7 += __shfl_down(aA7, 16);
        aB0 += __shfl_down(aB0, 16); aB1 += __shfl_down(aB1, 16);
        aB2 += __shfl_down(aB2, 16); aB3 += __shfl_down(aB3, 16);
        aB4 += __shfl_down(aB4, 16); aB5 += __shfl_down(aB5, 16);
        aB6 += __shfl_down(aB6, 16); aB7 += __shfl_down(aB7, 16);
        if (lane < 16) {
            uint4 oA, oB;
            oA.x = pack2(aA0, aA1); oA.y = pack2(aA2, aA3);
            oA.z = pack2(aA4, aA5); oA.w = pack2(aA6, aA7);
            oB.x = pack2(aB0, aB1); oB.y = pack2(aB2, aB3);
            oB.z = pack2(aB4, aB5); oB.w = pack2(aB6, aB7);
            *(uint4*)&At[(wv * 16 + 2 * p) * 128 + l16 * 8] = oA;
            *(uint4*)&At[(wv * 16 + 2 * p + 1) * 128 + l16 * 8] = oB;
        }
    }
    // no barrier: each wave reads only its own 16 rows below

    // ---- phase 2: MFMA GEMM1 (+relu) and GEMM2 ----
    const int lrow  = lane & 15;
    const int lquad = lane >> 4;

    short8 afrag[4];
#pragma unroll
    for (int ks = 0; ks < 4; ++ks)
        afrag[ks] = *(const short8*)&At[(wv * 16 + lrow) * 128 + ks * 32 + lquad * 8];
    float hreg[8][4];
#pragma unroll
    for (int nt = 0; nt < 8; ++nt) {
        f32x4 acc = {0.f, 0.f, 0.f, 0.f};
#pragma unroll
        for (int ks = 0; ks < 4; ++ks) {
            short8 bfr = *(const short8*)&w1t[(nt * 16 + lrow) * 128 + ks * 32 + lquad * 8];
            acc = __builtin_amdgcn_mfma_f32_16x16x32_bf16(afrag[ks], bfr, acc, 0, 0, 0);
        }
#pragma unroll
        for (int i = 0; i < 4; ++i) hreg[nt][i] = acc[i];
    }
#pragma unroll
    for (int nt = 0; nt < 8; ++nt) {
        int col = nt * 16 + lrow;
        float bb = b1l[col];
#pragma unroll
        for (int i = 0; i < 4; ++i) {
            int row = wv * 16 + lquad * 4 + i;
            At[row * 128 + col] = f2bf(fmaxf(hreg[nt][i] * dn[row] + bb, 0.f));
        }
    }
    // still wave-private (each wave reads back only its own rows)

#pragma unroll
    for (int ks = 0; ks < 4; ++ks)
        afrag[ks] = *(const short8*)&At[(wv * 16 + lrow) * 128 + ks * 32 + lquad * 8];
#pragma unroll
    for (int nt = 0; nt < 3; ++nt) {
        f32x4 acc = {0.f, 0.f, 0.f, 0.f};
#pragma unroll
        for (int ks = 0; ks < 4; ++ks) {
            short8 bfr = *(const short8*)&w2t[(nt * 16 + lrow) * 128 + ks * 32 + lquad * 8];
            acc = __builtin_amdgcn_mfma_f32_16x16x32_bf16(afrag[ks], bfr, acc, 0, 0, 0);
        }
        int col = nt * 16 + lrow;
        if (col < NC) {
#pragma unroll
            for (int i = 0; i < 4; ++i) {
                int row = wv * 16 + lquad * 4 + i;
                int grow = r0 + row;
                if (grow < NN)
                    hwb[(size_t)grow * NC + col] = f2bf(acc[i] * sn[row]);
            }
        }
    }
}

// one wave per node. lane = g*10+j (g<6, j<10): 6 edge slots, each edge's
// 80 B row read by 10 lanes as uint2 (4 bf16). Predicated 18-edge batches
// (3 independent loads per lane in flight); invalid slots clamp to edge `beg`
// with multiplicative zero mask. fp32 acc; shfl reduce into lanes 0..9,
// which store float4 with fused *dstn + b2.
__global__ __launch_bounds__(256) void gather2_kernel(const int* __restrict__ row_ptr,
                                                      const int* __restrict__ esrc,
                                                      const unsigned short* __restrict__ hwb,
                                                      const float* __restrict__ dst_norm,
                                                      const float* __restrict__ b2,
                                                      float* __restrict__ out) {
    int node = (blockIdx.x * blockDim.x + threadIdx.x) >> 6;
    int lane = threadIdx.x & 63;
    if (node >= NN) return;
    int beg = __builtin_amdgcn_readfirstlane(row_ptr[node]);
    int end = __builtin_amdgcn_readfirstlane(row_ptr[node + 1]);
    const int g = lane / 10;          // edge slot 0..5 (g==6: lanes 60-63 masked)
    const int j = lane - g * 10;      // uint2 index within 80 B row
    const bool active = (g < 6);
    float4 acc = make_float4(0.f, 0.f, 0.f, 0.f);
    for (int e = beg; e < end; e += 18) {
        const int rem = end - e;
        int s[3];
        float m[3];
#pragma unroll
        for (int q = 0; q < 3; ++q) {
            int slot = q * 6 + g;
            bool v = active && (slot < rem);
            int idx = v ? (e + slot) : beg;
            s[q] = esrc[idx];
            m[q] = v ? 1.f : 0.f;
        }
        uint2 u[3];
#pragma unroll
        for (int q = 0; q < 3; ++q)
            u[q] = ((const uint2*)(hwb + (size_t)s[q] * NC))[j];
#pragma unroll
        for (int q = 0; q < 3; ++q) {
            acc.x += bflo(u[q].x) * m[q];
            acc.y += bfhi(u[q].x) * m[q];
            acc.z += bflo(u[q].y) * m[q];
            acc.w += bfhi(u[q].y) * m[q];
        }
    }
    float4 tot = acc;
#pragma unroll
    for (int k = 1; k < 6; ++k) {
        tot.x += __shfl(acc.x, j + 10 * k);
        tot.y += __shfl(acc.y, j + 10 * k);
        tot.z += __shfl(acc.z, j + 10 * k);
        tot.w += __shfl(acc.w, j + 10 * k);
    }
    if (lane < 10) {
        float dnv = dst_norm[node];
        float4 bb = ((const float4*)b2)[j];
        float4 o;
        o.x = tot.x * dnv + bb.x;
        o.y = tot.y * dnv + bb.y;
        o.z = tot.z * dnv + bb.z;
        o.w = tot.w * dnv + bb.w;
        ((float4*)(out + (size_t)node * NC))[j] = o;
    }
}

extern "C" void kernel_launch(void* const* d_in, const int* in_sizes, int n_in,
                              void* d_out, int out_size, void* d_ws, size_t ws_size,
                              hipStream_t stream) {
    const float* x   = (const float*)d_in[0];
    const float* W1  = (const float*)d_in[1];
    const float* b1  = (const float*)d_in[2];
    const float* W2  = (const float*)d_in[3];
    const float* b2  = (const float*)d_in[4];
    const int*   src = (const int*)d_in[5];
    const int*   dst = (const int*)d_in[6];
    float* out = (float*)d_out;

    // workspace (4B units):
    // srcn[NN] | bcntD[256] | bcntS[256] | curD[256] | curS[256] |
    // baseD[256] | baseS[256] | row_ptr[NN+1] | dstn[NN] | esrc[NE] | pad |
    // xh[NN*64] | w1t[8192] | w2t[3072] | hwb[NN*20]
    float* srcn = (float*)d_ws;
    unsigned int* bcntD = (unsigned int*)(srcn + NN);
    unsigned int* bcntS = bcntD + 256;
    int* curD  = (int*)(bcntS + 256);
    int* curS  = curD + 256;
    int* baseD = curS + 256;
    int* baseS = baseD + 256;
    int* row_ptr = baseS + 256;
    float* dstn  = (float*)(row_ptr + NN + 1);
    int* esrc    = (int*)(dstn + NN);
    size_t ofs = (size_t)NN + 1536 + (NN + 1) + NN + NE;
    ofs = (ofs + 3) & ~(size_t)3;                 // 16B align
    unsigned short* xh   = (unsigned short*)((float*)d_ws + ofs);
    unsigned short* w1t  = xh + (size_t)NN * INF;
    unsigned short* w2t  = w1t + 128 * 128;
    unsigned short* hwb  = w2t + 48 * 128;

    // edge-record scratch lives in d_out (9.6 MB of 16 MB) — dead before gather2 writes
    int* epartsD = (int*)d_out;                            // 6.4 MB
    unsigned short* epartsS = (unsigned short*)(epartsD + NE);  // 3.2 MB

    hipMemsetAsync(bcntD, 0, 1024 * sizeof(int), stream);  // bcntD|bcntS|curD|curS

    histconv_kernel<<<HB + 6252, 256, 0, stream>>>(src, dst, bcntD, bcntS,
                                                   x, W1, W2, xh, w1t, w2t);
    basescan_kernel<<<1, 256, 0, stream>>>(bcntD, bcntS, baseD, baseS);
    partition_kernel<<<PBLK, 256, 0, stream>>>(src, dst, baseD, baseS, curD, curS,
                                               epartsD, epartsS);
    pass2_kernel<<<NBK, 512, 0, stream>>>(epartsD, epartsS, baseD, baseS,
                                          bcntD, bcntS, row_ptr, esrc, srcn, dstn);
    fused_kernel<<<(NN + 63) / 64, 256, 0, stream>>>(row_ptr, esrc, xh, srcn,
                                                     w1t, w2t, b1, dstn, hwb);
    gather2_kernel<<<(NN * 64 + 255) / 256, 256, 0, stream>>>(row_ptr, esrc, hwb,
                                                              dstn, b2, out);
}